// Round 11
// baseline (469.282 us; speedup 1.0000x reference)
//
#include <hip/hip_runtime.h>
#include <hip/hip_bf16.h>

// MoE layer: B=2,S=2048,D=1024,F=4096,E=8,K=2. T=4096 tokens.
// R11: 128x128 BK=64 4-wave grouped bf16 GEMM, 2-buffer 64KB LDS ->
// 2 blocks/CU (cross-block TLP = the only lever that measured; R6 family)
// with half the sync events of BK=32. k_init -> hipMemsetAsync; k_scan
// folded into k_assign. ksplit GEMM2 unchanged.

#define T_TOK 4096
#define D_DIM 1024
#define F_DIM 4096
#define E_NUM 8
#define CAP_ROWS 9216          // 8192 + 8*128 padding headroom
#define N_TILES (CAP_ROWS/128) // 72

typedef __attribute__((ext_vector_type(8))) short short8v;
typedef __attribute__((ext_vector_type(8))) unsigned short ushort8v;
typedef __attribute__((ext_vector_type(4))) float f32x4;

static __device__ __forceinline__ unsigned short f2bf(float f){
  union { float f; unsigned u; } v; v.f = f;
  unsigned r = (v.u + 0x7fffu + ((v.u >> 16) & 1u)) >> 16;  // RNE
  return (unsigned short)r;
}
static __device__ __forceinline__ float bf2f(unsigned short s){
  union { unsigned u; float f; } v; v.u = ((unsigned)s) << 16;
  return v.f;
}

static __device__ __forceinline__ void gload16(const void* g, void* l) {
  __builtin_amdgcn_global_load_lds(
      (const __attribute__((address_space(1))) unsigned int*)g,
      (__attribute__((address_space(3))) unsigned int*)l, 16, 0, 0);
}

// one wave per token: fp32 logits -> softmax -> probs + top-2; emits xbf too
__global__ __launch_bounds__(256) void k_router(
    const float* __restrict__ x, const float* __restrict__ Wr,
    const float* __restrict__ br, float* __restrict__ probs_out,
    int* __restrict__ topi, float* __restrict__ topw, int* __restrict__ counts,
    unsigned short* __restrict__ xbf)
{
  const int lane = threadIdx.x & 63;
  const int t = blockIdx.x * 4 + (threadIdx.x >> 6);
  float xv[16];
  #pragma unroll
  for (int i = 0; i < 16; ++i) xv[i] = x[(size_t)t*D_DIM + i*64 + lane];
  #pragma unroll
  for (int i = 0; i < 16; ++i) xbf[(size_t)t*D_DIM + i*64 + lane] = f2bf(xv[i]);
  float pe[E_NUM];
  #pragma unroll
  for (int e = 0; e < E_NUM; ++e) {
    float p = 0.f;
    #pragma unroll
    for (int i = 0; i < 16; ++i) p += xv[i] * Wr[(i*64 + lane)*E_NUM + e];
    #pragma unroll
    for (int off = 32; off >= 1; off >>= 1) p += __shfl_xor(p, off);
    pe[e] = p + br[e];
  }
  float m = pe[0];
  #pragma unroll
  for (int e = 1; e < E_NUM; ++e) m = fmaxf(m, pe[e]);
  float s = 0.f;
  #pragma unroll
  for (int e = 0; e < E_NUM; ++e) { pe[e] = expf(pe[e] - m); s += pe[e]; }
  const float inv = 1.f / s;
  int e1 = 0; float v1 = pe[0];
  #pragma unroll
  for (int e = 1; e < E_NUM; ++e) if (pe[e] > v1) { v1 = pe[e]; e1 = e; }
  int e2 = (e1 == 0) ? 1 : 0; float v2 = pe[e2];
  #pragma unroll
  for (int e = 0; e < E_NUM; ++e) if (e != e1 && pe[e] > v2) { v2 = pe[e]; e2 = e; }
  if (lane == 0) {
    #pragma unroll
    for (int e = 0; e < E_NUM; ++e) probs_out[(size_t)t*E_NUM + e] = pe[e] * inv;
    topi[t*2+0] = e1; topw[t*2+0] = v1 * inv;
    topi[t*2+1] = e2; topw[t*2+1] = v2 * inv;
    atomicAdd(&counts[e1], 1);
    atomicAdd(&counts[e2], 1);
  }
}

// assign with folded scan: every block recomputes 128-padded bases locally;
// block 0 also writes tile_e. cursor pre-zeroed by memset.
__global__ __launch_bounds__(256) void k_assign(
    const int* __restrict__ counts,
    const int* __restrict__ topi, const float* __restrict__ topw,
    int* __restrict__ cursor,
    int* __restrict__ rows_token, float* __restrict__ rows_w,
    int* __restrict__ pair_of, int* __restrict__ tile_e)
{
  __shared__ int base_s[E_NUM + 1];
  if (threadIdx.x == 0) {
    int base = 0;
    #pragma unroll
    for (int e = 0; e < E_NUM; ++e) {
      base_s[e] = base;
      base += ((counts[e] + 127) >> 7) << 7;
    }
    base_s[E_NUM] = base;
  }
  __syncthreads();
  if (blockIdx.x == 0 && threadIdx.x < N_TILES) {
    const int r0 = threadIdx.x << 7;
    int e = -1;
    #pragma unroll
    for (int k = 0; k < E_NUM; ++k)
      if (r0 >= base_s[k] && r0 < base_s[k+1]) e = k;
    tile_e[threadIdx.x] = e;
  }
  const int t = blockIdx.x * 256 + threadIdx.x;
  if (t < T_TOK) {
    #pragma unroll
    for (int k = 0; k < 2; ++k) {
      const int e = topi[t*2+k];
      const int slot = atomicAdd(&cursor[e], 1);
      const int pid = base_s[e] + slot;
      rows_token[pid] = t;
      rows_w[pid] = topw[t*2+k];
      pair_of[t*2+k] = pid;
    }
  }
}

// transpose + convert: per expert, in fp32 [R][C] -> out bf16 [C][R]
template<int R, int C>
__global__ __launch_bounds__(256) void k_tcvt(const float* __restrict__ in,
                                              unsigned short* __restrict__ out)
{
  const size_t eo = (size_t)blockIdx.z * R * C;
  const int r0 = blockIdx.y * 64, c0 = blockIdx.x * 64;
  __shared__ unsigned short ls[64][66];
  const int t = threadIdx.x;
  const int rr = t >> 4, cc = (t & 15) * 4;
  #pragma unroll
  for (int p = 0; p < 4; ++p) {
    const float4 v = *(const float4*)&in[eo + (size_t)(r0 + p*16 + rr)*C + c0 + cc];
    ls[p*16+rr][cc+0]=f2bf(v.x); ls[p*16+rr][cc+1]=f2bf(v.y);
    ls[p*16+rr][cc+2]=f2bf(v.z); ls[p*16+rr][cc+3]=f2bf(v.w);
  }
  __syncthreads();
  const int kc = (t & 7) * 8, nn0 = t >> 3;
  #pragma unroll
  for (int p = 0; p < 2; ++p) {
    const int nn = nn0 + p*32;
    ushort8v o;
    #pragma unroll
    for (int j = 0; j < 8; ++j) o[j] = ls[kc + j][nn];
    *(ushort8v*)&out[eo + (size_t)(c0 + nn)*R + r0 + kc] = o;
  }
}

// grouped bf16 MFMA GEMM: BM=BN=128, BK=64, 4 waves (2Mx2N, wave 64x64),
// 2-buffer LDS (64KB -> 2 blocks/CU). Per iter: stage(t+1)->buf^1, 16 ds_read,
// 32 MFMA (setprio), vmcnt(0), barrier. XOR swizzle (proven 0-conflict).
// C[r,n] = sum_k A[r,k]*Bt[n,k].
// EPI 1: relu(acc+bias) -> h.   EPI 2: (acc + (z==0)*bias)*rows_w -> ypart[z].
template<bool GATHER, int NDIM, int KFULL, int EPI>
__global__ __launch_bounds__(256, 2) void k_gemm(
    const unsigned short* __restrict__ A,
    const unsigned short* __restrict__ Bt,   // per-expert [NDIM][KFULL] bf16
    const float* __restrict__ bias,          // [E][NDIM]
    const int* __restrict__ tile_e,
    const int* __restrict__ rows_token,
    const float* __restrict__ rows_w,
    unsigned short* __restrict__ outp,
    int nkt, int kch)
{
  // XCD-bijective swizzle, B-panel-major (proven FETCH cut). tot%8==0.
  const int tot = gridDim.x * gridDim.y;
  int flat = blockIdx.x * gridDim.y + blockIdx.y;
  flat = (flat & 7) * (tot >> 3) + (flat >> 3);
  const int bx = flat / gridDim.y;
  const int by = flat % gridDim.y;
  const int e = tile_e[by];
  if (e < 0) return;
  const int rt = by * 128;
  const int ntc = bx * 128;
  const int koff = blockIdx.z * kch;
  // buffer: rows 0-127 = A-tile (128x64), rows 128-255 = B-tile. 32KB each.
  __shared__ __align__(16) unsigned short LB[2][256 * 64];
  const int tid = threadIdx.x;
  const int lane = tid & 63;
  const int w = tid >> 6;
  // staging: waves 0-1 -> A rows [w*64, w*64+64); waves 2-3 -> B same.
  // 8 calls/wave/K-tile, call = 8 rows x 128B; lane -> row=lane>>3, chunk
  // pre-swizzled g = (lane&7) ^ (lane>>3).
  const int lr = lane >> 3;
  const int g  = (lane & 7) ^ lr;
  const unsigned short* gp[8];
  unsigned lbase[8];
  if (w < 2) {
    #pragma unroll
    for (int i = 0; i < 8; ++i) {
      const int rl = w*64 + i*8 + lr;
      const int rowidx = GATHER ? rows_token[rt + rl] : (rt + rl);
      gp[i] = A + (size_t)rowidx * KFULL + koff + g*8;
      lbase[i] = (unsigned)((w*64 + i*8) * 64);
    }
  } else {
    const unsigned short* Be = Bt + (size_t)e * NDIM * KFULL;
    #pragma unroll
    for (int i = 0; i < 8; ++i) {
      const int rl = (w-2)*64 + i*8 + lr;
      gp[i] = Be + (size_t)(ntc + rl) * KFULL + koff + g*8;
      lbase[i] = (unsigned)((128*64) + ((w-2)*64 + i*8) * 64);
    }
  }
  const int wr = w >> 1, wc = w & 1;       // 2M x 2N, wave tile 64x64
  const int cl = lane & 15, rgb = lane >> 4;
  const int sz = cl & 7;                   // read-side XOR (row&7 == cl&7)
  f32x4 acc[4][4] = {};

  #define STG8(tt, bb)                                          \
    { const int _ko = (tt) * 64;                                \
      _Pragma("unroll")                                         \
      for (int _i = 0; _i < 8; ++_i)                            \
        gload16(gp[_i] + _ko, &LB[bb][lbase[_i]]); }

  // prologue: stage tile 0 -> buf 0; certify; barrier
  STG8(0, 0)
  asm volatile("s_waitcnt vmcnt(0)" ::: "memory");
  __builtin_amdgcn_s_barrier();

  for (int t = 0; t < nkt; ++t) {
    const int bb = t & 1;
    if (t + 1 < nkt) STG8(t+1, bb^1)       // flies under reads+MFMA
    const unsigned short* Sb = &LB[bb][0];
    short8v a[4][2], b[4][2];
    #pragma unroll
    for (int m = 0; m < 4; ++m) {
      a[m][0] = *(const short8v*)&Sb[(wr*64 + m*16 + cl)*64 + ((0*4+rgb)^sz)*8];
      a[m][1] = *(const short8v*)&Sb[(wr*64 + m*16 + cl)*64 + ((1*4+rgb)^sz)*8];
    }
    #pragma unroll
    for (int n = 0; n < 4; ++n) {
      b[n][0] = *(const short8v*)&Sb[(128*64) + (wc*64 + n*16 + cl)*64 + ((0*4+rgb)^sz)*8];
      b[n][1] = *(const short8v*)&Sb[(128*64) + (wc*64 + n*16 + cl)*64 + ((1*4+rgb)^sz)*8];
    }
    __builtin_amdgcn_s_setprio(1);
    #pragma unroll
    for (int m = 0; m < 4; ++m)
      #pragma unroll
      for (int n = 0; n < 4; ++n) {
        acc[m][n] = __builtin_amdgcn_mfma_f32_16x16x32_bf16(a[m][0], b[n][0], acc[m][n], 0, 0, 0);
        acc[m][n] = __builtin_amdgcn_mfma_f32_16x16x32_bf16(a[m][1], b[n][1], acc[m][n], 0, 0, 0);
      }
    __builtin_amdgcn_s_setprio(0);
    asm volatile("s_waitcnt vmcnt(0)" ::: "memory");   // t+1 landed
    __builtin_amdgcn_s_barrier();
  }
  #undef STG8

  // epilogue: C/D layout col = lane&15, row = (lane>>4)*4 + reg  [m89]
  // pack bf16 pairs across lane^1 -> dword stores from even lanes
  unsigned short* op = outp;
  if (EPI == 2) op += (size_t)blockIdx.z * CAP_ROWS * NDIM;
  const bool addb = (EPI == 1) || (blockIdx.z == 0);
  const size_t ebias = (size_t)e * NDIM;
  #pragma unroll
  for (int m = 0; m < 4; ++m) {
    const int row = rt + wr*64 + m*16 + rgb*4;
    float4 rw4 = make_float4(0,0,0,0);
    if (EPI == 2) rw4 = *(const float4*)&rows_w[row];
    #pragma unroll
    for (int n = 0; n < 4; ++n) {
      const int col = ntc + wc*64 + n*16 + cl;
      const float bv = addb ? bias[ebias + col] : 0.f;
      #pragma unroll
      for (int r = 0; r < 4; ++r) {
        float v = acc[m][n][r] + bv;
        if (EPI == 1) v = fmaxf(v, 0.f);
        else          v *= ((const float*)&rw4)[r];
        const unsigned short hb = f2bf(v);
        const unsigned short ob = (unsigned short)__shfl_xor((int)(unsigned)hb, 1);
        if ((lane & 1) == 0) {
          const unsigned pk = (unsigned)hb | ((unsigned)ob << 16);
          *(unsigned*)&op[(size_t)(row + r)*NDIM + col] = pk;
        }
      }
    }
  }
}

// out[t] = sum_k sum_s ypart[s][pair_k(t)]  (fixed order -> deterministic)
__global__ __launch_bounds__(256) void k_combine(
    const unsigned short* __restrict__ yp, const int* __restrict__ pair_of,
    float* __restrict__ out, int ksplit)
{
  const int gid = blockIdx.x * 256 + threadIdx.x;   // T*D/8 threads
  const int t = gid >> 7;
  const int c = (gid & 127) * 8;
  float o[8] = {0,0,0,0,0,0,0,0};
  #pragma unroll
  for (int k = 0; k < 2; ++k) {
    const int p = pair_of[t*2+k];
    for (int s = 0; s < ksplit; ++s) {
      const ushort8v v = *(const ushort8v*)&yp[((size_t)s*CAP_ROWS + p)*D_DIM + c];
      #pragma unroll
      for (int j = 0; j < 8; ++j) o[j] += bf2f(v[j]);
    }
  }
  float4 o0; o0.x=o[0]; o0.y=o[1]; o0.z=o[2]; o0.w=o[3];
  float4 o1; o1.x=o[4]; o1.y=o[5]; o1.z=o[6]; o1.w=o[7];
  *(float4*)&out[(size_t)t*D_DIM + c]     = o0;
  *(float4*)&out[(size_t)t*D_DIM + c + 4] = o1;
}

extern "C" void kernel_launch(void* const* d_in, const int* in_sizes, int n_in,
                              void* d_out, int out_size, void* d_ws, size_t ws_size,
                              hipStream_t stream)
{
  const float* x  = (const float*)d_in[0];
  const float* Wr = (const float*)d_in[1];
  const float* br = (const float*)d_in[2];
  const float* W1 = (const float*)d_in[3];
  const float* b1 = (const float*)d_in[4];
  const float* W2 = (const float*)d_in[5];
  const float* b2 = (const float*)d_in[6];
  (void)in_sizes; (void)n_in; (void)out_size;

  float* out   = (float*)d_out;
  float* probs = out + (size_t)T_TOK * D_DIM;

  char* w = (char*)d_ws;
  size_t off = 0;
  // contiguous zero-init region: counts, cursor, rows_token, rows_w
  int*   counts     = (int*)(w + off); off += 256;
  int*   cursor     = (int*)(w + off); off += 256;
  int*   rows_token = (int*)(w + off); off += (size_t)CAP_ROWS*4;
  float* rows_w     = (float*)(w + off); off += (size_t)CAP_ROWS*4;
  const size_t zbytes = off;
  int*   tile_e     = (int*)(w + off); off += 3072;
  int*   topi       = (int*)(w + off); off += (size_t)T_TOK*2*4;
  float* topw       = (float*)(w + off); off += (size_t)T_TOK*2*4;
  int*   pair_of    = (int*)(w + off); off += (size_t)T_TOK*2*4;
  off = (off + 255) & ~(size_t)255;
  unsigned short* xbf = (unsigned short*)(w + off); off += (size_t)T_TOK*D_DIM*2;
  unsigned short* Wt  = (unsigned short*)(w + off); off += (size_t)E_NUM*D_DIM*F_DIM*2;
  unsigned short* h   = (unsigned short*)(w + off); off += (size_t)CAP_ROWS*F_DIM*2;
  unsigned short* yp  = (unsigned short*)(w + off);
  // choose GEMM2 K-split by available workspace (deterministic per run)
  const size_t ypart_bytes = (size_t)CAP_ROWS * D_DIM * 2;
  int ksplit = 1;
  if (ws_size >= off + 4 * ypart_bytes) ksplit = 4;
  else if (ws_size >= off + 2 * ypart_bytes) ksplit = 2;
  const int kch2 = F_DIM / ksplit;
  const int nkt2 = kch2 / 64;

  hipMemsetAsync(d_ws, 0, zbytes, stream);
  k_router<<<T_TOK / 4, 256, 0, stream>>>(x, Wr, br, probs, topi, topw, counts, xbf);
  k_assign<<<T_TOK / 256, 256, 0, stream>>>(counts, topi, topw, cursor,
                                            rows_token, rows_w, pair_of, tile_e);
  // W1 [E][D][F] -> Wt [E][F][D] bf16
  k_tcvt<D_DIM, F_DIM><<<dim3(F_DIM/64, D_DIM/64, E_NUM), 256, 0, stream>>>(W1, Wt);
  // GEMM1: tiles 128x128, K=1024 (nkt=16); grid 32x72
  k_gemm<true, F_DIM, D_DIM, 1><<<dim3(F_DIM/128, N_TILES, 1), 256, 0, stream>>>(
      xbf, Wt, b1, tile_e, rows_token, rows_w, h, D_DIM/64, D_DIM);
  // W2 [E][F][D] -> Wt [E][D][F] bf16 (overwrites W1t; stream-ordered)
  k_tcvt<F_DIM, D_DIM><<<dim3(D_DIM/64, F_DIM/64, E_NUM), 256, 0, stream>>>(W2, Wt);
  // GEMM2: tiles 128x128, K split into ksplit chunks along blockIdx.z
  k_gemm<false, D_DIM, F_DIM, 2><<<dim3(D_DIM/128, N_TILES, ksplit), 256, 0, stream>>>(
      h, Wt, b2, tile_e, rows_token, rows_w, yp, nkt2, kch2);
  k_combine<<<T_TOK * D_DIM / 8 / 256, 256, 0, stream>>>(yp, pair_of, out, ksplit);
}

// Round 12
// 452.101 us; speedup vs baseline: 1.0380x; 1.0380x over previous
//
#include <hip/hip_runtime.h>
#include <hip/hip_bf16.h>

// MoE layer: B=2,S=2048,D=1024,F=4096,E=8,K=2. T=4096 tokens.
// R12: persistent-CTA grouped GEMM (512 blocks = 2/CU, grid-stride over
// tiles, XCD-chunked tile ownership) on R11's proven 128x128 BK=64 core.
// ksplit capped at 2 (deterministic). Tail rounds eliminated.

#define T_TOK 4096
#define D_DIM 1024
#define F_DIM 4096
#define E_NUM 8
#define CAP_ROWS 9216          // 8192 + 8*128 padding headroom
#define N_TILES (CAP_ROWS/128) // 72
#define PGRID 512              // persistent blocks = 2/CU x 256 CU

typedef __attribute__((ext_vector_type(8))) short short8v;
typedef __attribute__((ext_vector_type(8))) unsigned short ushort8v;
typedef __attribute__((ext_vector_type(4))) float f32x4;

static __device__ __forceinline__ unsigned short f2bf(float f){
  union { float f; unsigned u; } v; v.f = f;
  unsigned r = (v.u + 0x7fffu + ((v.u >> 16) & 1u)) >> 16;  // RNE
  return (unsigned short)r;
}
static __device__ __forceinline__ float bf2f(unsigned short s){
  union { unsigned u; float f; } v; v.u = ((unsigned)s) << 16;
  return v.f;
}

static __device__ __forceinline__ void gload16(const void* g, void* l) {
  __builtin_amdgcn_global_load_lds(
      (const __attribute__((address_space(1))) unsigned int*)g,
      (__attribute__((address_space(3))) unsigned int*)l, 16, 0, 0);
}

// one wave per token: fp32 logits -> softmax -> probs + top-2; emits xbf too
__global__ __launch_bounds__(256) void k_router(
    const float* __restrict__ x, const float* __restrict__ Wr,
    const float* __restrict__ br, float* __restrict__ probs_out,
    int* __restrict__ topi, float* __restrict__ topw, int* __restrict__ counts,
    unsigned short* __restrict__ xbf)
{
  const int lane = threadIdx.x & 63;
  const int t = blockIdx.x * 4 + (threadIdx.x >> 6);
  float xv[16];
  #pragma unroll
  for (int i = 0; i < 16; ++i) xv[i] = x[(size_t)t*D_DIM + i*64 + lane];
  #pragma unroll
  for (int i = 0; i < 16; ++i) xbf[(size_t)t*D_DIM + i*64 + lane] = f2bf(xv[i]);
  float pe[E_NUM];
  #pragma unroll
  for (int e = 0; e < E_NUM; ++e) {
    float p = 0.f;
    #pragma unroll
    for (int i = 0; i < 16; ++i) p += xv[i] * Wr[(i*64 + lane)*E_NUM + e];
    #pragma unroll
    for (int off = 32; off >= 1; off >>= 1) p += __shfl_xor(p, off);
    pe[e] = p + br[e];
  }
  float m = pe[0];
  #pragma unroll
  for (int e = 1; e < E_NUM; ++e) m = fmaxf(m, pe[e]);
  float s = 0.f;
  #pragma unroll
  for (int e = 0; e < E_NUM; ++e) { pe[e] = expf(pe[e] - m); s += pe[e]; }
  const float inv = 1.f / s;
  int e1 = 0; float v1 = pe[0];
  #pragma unroll
  for (int e = 1; e < E_NUM; ++e) if (pe[e] > v1) { v1 = pe[e]; e1 = e; }
  int e2 = (e1 == 0) ? 1 : 0; float v2 = pe[e2];
  #pragma unroll
  for (int e = 0; e < E_NUM; ++e) if (e != e1 && pe[e] > v2) { v2 = pe[e]; e2 = e; }
  if (lane == 0) {
    #pragma unroll
    for (int e = 0; e < E_NUM; ++e) probs_out[(size_t)t*E_NUM + e] = pe[e] * inv;
    topi[t*2+0] = e1; topw[t*2+0] = v1 * inv;
    topi[t*2+1] = e2; topw[t*2+1] = v2 * inv;
    atomicAdd(&counts[e1], 1);
    atomicAdd(&counts[e2], 1);
  }
}

// assign with folded scan: every block recomputes 128-padded bases locally;
// block 0 also writes tile_e. cursor pre-zeroed by memset.
__global__ __launch_bounds__(256) void k_assign(
    const int* __restrict__ counts,
    const int* __restrict__ topi, const float* __restrict__ topw,
    int* __restrict__ cursor,
    int* __restrict__ rows_token, float* __restrict__ rows_w,
    int* __restrict__ pair_of, int* __restrict__ tile_e)
{
  __shared__ int base_s[E_NUM + 1];
  if (threadIdx.x == 0) {
    int base = 0;
    #pragma unroll
    for (int e = 0; e < E_NUM; ++e) {
      base_s[e] = base;
      base += ((counts[e] + 127) >> 7) << 7;
    }
    base_s[E_NUM] = base;
  }
  __syncthreads();
  if (blockIdx.x == 0 && threadIdx.x < N_TILES) {
    const int r0 = threadIdx.x << 7;
    int e = -1;
    #pragma unroll
    for (int k = 0; k < E_NUM; ++k)
      if (r0 >= base_s[k] && r0 < base_s[k+1]) e = k;
    tile_e[threadIdx.x] = e;
  }
  const int t = blockIdx.x * 256 + threadIdx.x;
  if (t < T_TOK) {
    #pragma unroll
    for (int k = 0; k < 2; ++k) {
      const int e = topi[t*2+k];
      const int slot = atomicAdd(&cursor[e], 1);
      const int pid = base_s[e] + slot;
      rows_token[pid] = t;
      rows_w[pid] = topw[t*2+k];
      pair_of[t*2+k] = pid;
    }
  }
}

// transpose + convert: per expert, in fp32 [R][C] -> out bf16 [C][R]
template<int R, int C>
__global__ __launch_bounds__(256) void k_tcvt(const float* __restrict__ in,
                                              unsigned short* __restrict__ out)
{
  const size_t eo = (size_t)blockIdx.z * R * C;
  const int r0 = blockIdx.y * 64, c0 = blockIdx.x * 64;
  __shared__ unsigned short ls[64][66];
  const int t = threadIdx.x;
  const int rr = t >> 4, cc = (t & 15) * 4;
  #pragma unroll
  for (int p = 0; p < 4; ++p) {
    const float4 v = *(const float4*)&in[eo + (size_t)(r0 + p*16 + rr)*C + c0 + cc];
    ls[p*16+rr][cc+0]=f2bf(v.x); ls[p*16+rr][cc+1]=f2bf(v.y);
    ls[p*16+rr][cc+2]=f2bf(v.z); ls[p*16+rr][cc+3]=f2bf(v.w);
  }
  __syncthreads();
  const int kc = (t & 7) * 8, nn0 = t >> 3;
  #pragma unroll
  for (int p = 0; p < 2; ++p) {
    const int nn = nn0 + p*32;
    ushort8v o;
    #pragma unroll
    for (int j = 0; j < 8; ++j) o[j] = ls[kc + j][nn];
    *(ushort8v*)&out[eo + (size_t)(c0 + nn)*R + r0 + kc] = o;
  }
}

// persistent grouped bf16 MFMA GEMM: BM=BN=128, BK=64, 4 waves (2Mx2N),
// 2-buffer 64KB LDS (2 blocks/CU). Grid-stride over tiles, XCD-chunked:
// XCD q owns tiles [q*tot/8,(q+1)*tot/8), B-panel-major within region.
// Per K-tile: stage(t+1)->buf^1, 16 ds_read, 32 MFMA (setprio), vmcnt(0), bar.
// C[r,n] = sum_k A[r,k]*Bt[n,k].
// EPI 1: relu(acc+bias) -> h.   EPI 2: (acc + (z==0)*bias)*rows_w -> ypart[z].
template<bool GATHER, int NDIM, int KFULL, int EPI>
__global__ __launch_bounds__(256, 2) void k_gemm(
    const unsigned short* __restrict__ A,
    const unsigned short* __restrict__ Bt,   // per-expert [NDIM][KFULL] bf16
    const float* __restrict__ bias,          // [E][NDIM]
    const int* __restrict__ tile_e,
    const int* __restrict__ rows_token,
    const float* __restrict__ rows_w,
    unsigned short* __restrict__ outp,
    int tot, int nbx, int nkt, int kch)
{
  const int q = blockIdx.x & 7;            // XCD (dispatch round-robin %8)
  const int bslot = blockIdx.x >> 3;       // 0..63 within XCD
  const int region = tot >> 3;             // tiles per XCD
  const int cpq = region / N_TILES;        // (bx,z)-combos per XCD
  __shared__ __align__(16) unsigned short LB[2][256 * 64];
  const int tid = threadIdx.x;
  const int lane = tid & 63;
  const int w = tid >> 6;
  const int lr = lane >> 3;
  const int g  = (lane & 7) ^ lr;          // pre-swizzled 16B chunk
  unsigned lbase[8];
  if (w < 2) {
    #pragma unroll
    for (int i = 0; i < 8; ++i) lbase[i] = (unsigned)((w*64 + i*8) * 64);
  } else {
    #pragma unroll
    for (int i = 0; i < 8; ++i) lbase[i] = (unsigned)((128*64) + ((w-2)*64 + i*8) * 64);
  }
  const int wr = w >> 1, wc = w & 1;       // 2M x 2N, wave tile 64x64
  const int cl = lane & 15, rgb = lane >> 4;
  const int sz = cl & 7;                   // read-side XOR (row&7 == cl&7)

  for (int tw = bslot; tw < region; tw += (PGRID >> 3)) {
    const int combo = q * cpq + tw / N_TILES;
    const int by = tw % N_TILES;
    const int bx = combo % nbx;
    const int z  = combo / nbx;
    const int e = tile_e[by];
    if (e < 0) continue;
    const int rt = by * 128;
    const int ntc = bx * 128;
    const int koff = z * kch;
    // per-tile source pointers
    const unsigned short* gp[8];
    if (w < 2) {
      #pragma unroll
      for (int i = 0; i < 8; ++i) {
        const int rl = w*64 + i*8 + lr;
        const int rowidx = GATHER ? rows_token[rt + rl] : (rt + rl);
        gp[i] = A + (size_t)rowidx * KFULL + koff + g*8;
      }
    } else {
      const unsigned short* Be = Bt + (size_t)e * NDIM * KFULL;
      #pragma unroll
      for (int i = 0; i < 8; ++i) {
        const int rl = (w-2)*64 + i*8 + lr;
        gp[i] = Be + (size_t)(ntc + rl) * KFULL + koff + g*8;
      }
    }
    f32x4 acc[4][4] = {};

    #define STG8(tt, bb)                                          \
      { const int _ko = (tt) * 64;                                \
        _Pragma("unroll")                                         \
        for (int _i = 0; _i < 8; ++_i)                            \
          gload16(gp[_i] + _ko, &LB[bb][lbase[_i]]); }

    STG8(0, 0)
    asm volatile("s_waitcnt vmcnt(0)" ::: "memory");
    __builtin_amdgcn_s_barrier();

    for (int t = 0; t < nkt; ++t) {
      const int bb = t & 1;
      if (t + 1 < nkt) STG8(t+1, bb^1)     // flies under reads+MFMA
      const unsigned short* Sb = &LB[bb][0];
      short8v a[4][2], b[4][2];
      #pragma unroll
      for (int m = 0; m < 4; ++m) {
        a[m][0] = *(const short8v*)&Sb[(wr*64 + m*16 + cl)*64 + ((0*4+rgb)^sz)*8];
        a[m][1] = *(const short8v*)&Sb[(wr*64 + m*16 + cl)*64 + ((1*4+rgb)^sz)*8];
      }
      #pragma unroll
      for (int n = 0; n < 4; ++n) {
        b[n][0] = *(const short8v*)&Sb[(128*64) + (wc*64 + n*16 + cl)*64 + ((0*4+rgb)^sz)*8];
        b[n][1] = *(const short8v*)&Sb[(128*64) + (wc*64 + n*16 + cl)*64 + ((1*4+rgb)^sz)*8];
      }
      __builtin_amdgcn_s_setprio(1);
      #pragma unroll
      for (int m = 0; m < 4; ++m)
        #pragma unroll
        for (int n = 0; n < 4; ++n) {
          acc[m][n] = __builtin_amdgcn_mfma_f32_16x16x32_bf16(a[m][0], b[n][0], acc[m][n], 0, 0, 0);
          acc[m][n] = __builtin_amdgcn_mfma_f32_16x16x32_bf16(a[m][1], b[n][1], acc[m][n], 0, 0, 0);
        }
      __builtin_amdgcn_s_setprio(0);
      asm volatile("s_waitcnt vmcnt(0)" ::: "memory");   // t+1 landed
      __builtin_amdgcn_s_barrier();
    }
    #undef STG8

    // epilogue: C/D layout col = lane&15, row = (lane>>4)*4 + reg  [m89]
    unsigned short* op = outp;
    if (EPI == 2) op += (size_t)z * CAP_ROWS * NDIM;
    const bool addb = (EPI == 1) || (z == 0);
    const size_t ebias = (size_t)e * NDIM;
    #pragma unroll
    for (int m = 0; m < 4; ++m) {
      const int row = rt + wr*64 + m*16 + rgb*4;
      float4 rw4 = make_float4(0,0,0,0);
      if (EPI == 2) rw4 = *(const float4*)&rows_w[row];
      #pragma unroll
      for (int n = 0; n < 4; ++n) {
        const int col = ntc + wc*64 + n*16 + cl;
        const float bv = addb ? bias[ebias + col] : 0.f;
        #pragma unroll
        for (int r = 0; r < 4; ++r) {
          float v = acc[m][n][r] + bv;
          if (EPI == 1) v = fmaxf(v, 0.f);
          else          v *= ((const float*)&rw4)[r];
          const unsigned short hb = f2bf(v);
          const unsigned short ob = (unsigned short)__shfl_xor((int)(unsigned)hb, 1);
          if ((lane & 1) == 0) {
            const unsigned pk = (unsigned)hb | ((unsigned)ob << 16);
            *(unsigned*)&op[(size_t)(row + r)*NDIM + col] = pk;
          }
        }
      }
    }
  }
}

// out[t] = sum_k sum_s ypart[s][pair_k(t)]  (fixed order -> deterministic)
__global__ __launch_bounds__(256) void k_combine(
    const unsigned short* __restrict__ yp, const int* __restrict__ pair_of,
    float* __restrict__ out, int ksplit)
{
  const int gid = blockIdx.x * 256 + threadIdx.x;   // T*D/8 threads
  const int t = gid >> 7;
  const int c = (gid & 127) * 8;
  float o[8] = {0,0,0,0,0,0,0,0};
  #pragma unroll
  for (int k = 0; k < 2; ++k) {
    const int p = pair_of[t*2+k];
    for (int s = 0; s < ksplit; ++s) {
      const ushort8v v = *(const ushort8v*)&yp[((size_t)s*CAP_ROWS + p)*D_DIM + c];
      #pragma unroll
      for (int j = 0; j < 8; ++j) o[j] += bf2f(v[j]);
    }
  }
  float4 o0; o0.x=o[0]; o0.y=o[1]; o0.z=o[2]; o0.w=o[3];
  float4 o1; o1.x=o[4]; o1.y=o[5]; o1.z=o[6]; o1.w=o[7];
  *(float4*)&out[(size_t)t*D_DIM + c]     = o0;
  *(float4*)&out[(size_t)t*D_DIM + c + 4] = o1;
}

extern "C" void kernel_launch(void* const* d_in, const int* in_sizes, int n_in,
                              void* d_out, int out_size, void* d_ws, size_t ws_size,
                              hipStream_t stream)
{
  const float* x  = (const float*)d_in[0];
  const float* Wr = (const float*)d_in[1];
  const float* br = (const float*)d_in[2];
  const float* W1 = (const float*)d_in[3];
  const float* b1 = (const float*)d_in[4];
  const float* W2 = (const float*)d_in[5];
  const float* b2 = (const float*)d_in[6];
  (void)in_sizes; (void)n_in; (void)out_size;

  float* out   = (float*)d_out;
  float* probs = out + (size_t)T_TOK * D_DIM;

  char* w = (char*)d_ws;
  size_t off = 0;
  // contiguous zero-init region: counts, cursor, rows_token, rows_w
  int*   counts     = (int*)(w + off); off += 256;
  int*   cursor     = (int*)(w + off); off += 256;
  int*   rows_token = (int*)(w + off); off += (size_t)CAP_ROWS*4;
  float* rows_w     = (float*)(w + off); off += (size_t)CAP_ROWS*4;
  const size_t zbytes = off;
  int*   tile_e     = (int*)(w + off); off += 3072;
  int*   topi       = (int*)(w + off); off += (size_t)T_TOK*2*4;
  float* topw       = (float*)(w + off); off += (size_t)T_TOK*2*4;
  int*   pair_of    = (int*)(w + off); off += (size_t)T_TOK*2*4;
  off = (off + 255) & ~(size_t)255;
  unsigned short* xbf = (unsigned short*)(w + off); off += (size_t)T_TOK*D_DIM*2;
  unsigned short* Wt  = (unsigned short*)(w + off); off += (size_t)E_NUM*D_DIM*F_DIM*2;
  unsigned short* h   = (unsigned short*)(w + off); off += (size_t)CAP_ROWS*F_DIM*2;
  unsigned short* yp  = (unsigned short*)(w + off);
  // GEMM2 K-split: deterministic, capped at 2
  const size_t ypart_bytes = (size_t)CAP_ROWS * D_DIM * 2;
  const int ksplit = (ws_size >= off + 2 * ypart_bytes) ? 2 : 1;
  const int kch2 = F_DIM / ksplit;
  const int nkt2 = kch2 / 64;

  hipMemsetAsync(d_ws, 0, zbytes, stream);
  k_router<<<T_TOK / 4, 256, 0, stream>>>(x, Wr, br, probs, topi, topw, counts, xbf);
  k_assign<<<T_TOK / 256, 256, 0, stream>>>(counts, topi, topw, cursor,
                                            rows_token, rows_w, pair_of, tile_e);
  // W1 [E][D][F] -> Wt [E][F][D] bf16
  k_tcvt<D_DIM, F_DIM><<<dim3(F_DIM/64, D_DIM/64, E_NUM), 256, 0, stream>>>(W1, Wt);
  // GEMM1: tot = 32x72 = 2304 tiles, persistent 512 blocks
  k_gemm<true, F_DIM, D_DIM, 1><<<PGRID, 256, 0, stream>>>(
      xbf, Wt, b1, tile_e, rows_token, rows_w, h,
      (F_DIM/128)*N_TILES, F_DIM/128, D_DIM/64, D_DIM);
  // W2 [E][F][D] -> Wt [E][D][F] bf16 (overwrites W1t; stream-ordered)
  k_tcvt<F_DIM, D_DIM><<<dim3(D_DIM/64, F_DIM/64, E_NUM), 256, 0, stream>>>(W2, Wt);
  // GEMM2: tot = 8x72xksplit tiles, persistent 512 blocks
  k_gemm<false, D_DIM, F_DIM, 2><<<PGRID, 256, 0, stream>>>(
      h, Wt, b2, tile_e, rows_token, rows_w, yp,
      (D_DIM/128)*N_TILES*ksplit, D_DIM/128, nkt2, kch2);
  k_combine<<<T_TOK * D_DIM / 8 / 256, 256, 0, stream>>>(yp, pair_of, out, ksplit);
}